// Round 1
// baseline (410.342 us; speedup 1.0000x reference)
//
#include <hip/hip_runtime.h>
#include <stdint.h>

typedef unsigned long long u64;
typedef unsigned int u32;

#define HW 65536   // 256*256
#define WD 256

// ---------------------------------------------------------------------------
// Kernel 1: pack weights. scale[o] = mean|w[o]|, pw[o][k] bit i = signbit(w[o][i][kh][kw])
// w layout: (O=64, I=64, kh=3, kw=3) -> flat o*576 + i*9 + k
// ---------------------------------------------------------------------------
__global__ __launch_bounds__(64) void pack_w_kernel(const float* __restrict__ wt,
                                                    u64* __restrict__ pw,
                                                    float* __restrict__ scale) {
    const int o = threadIdx.x;
    u64 pk[9];
#pragma unroll
    for (int k = 0; k < 9; k++) pk[k] = 0ull;
    float s = 0.f;
    const float* p = wt + o * 576;
    for (int i = 0; i < 64; i++) {
#pragma unroll
        for (int k = 0; k < 9; k++) {
            float v = p[i * 9 + k];
            s += fabsf(v);
            pk[k] |= (u64)(__float_as_uint(v) >> 31) << i;
        }
    }
#pragma unroll
    for (int k = 0; k < 9; k++) pw[o * 9 + k] = pk[k];
    scale[o] = s * (1.0f / 576.0f);
}

// ---------------------------------------------------------------------------
// Kernel 2: pack activations WITH the temporal channel shift folded in.
// y[n=(b,t)][c] = x[b*3+(t+2)%3][32+c]      for c in [0,32)   -> bits 0..31
//              = x[n][c-32]                 for c in [32,64)  -> bits 32..63
// Each thread packs 4 consecutive spatial positions via float4 loads.
// ---------------------------------------------------------------------------
__global__ __launch_bounds__(256) void pack_x_kernel(const float* __restrict__ x,
                                                     u64* __restrict__ px) {
    const int n = blockIdx.x >> 6;                               // frame 0..11
    const int s = ((blockIdx.x & 63) << 10) + (threadIdx.x << 2); // spatial pos, 4/thread
    const int b = n / 3;
    const int t = n - b * 3;
    const int fp = b * 3 + (t + 2) % 3;                          // source frame for low bits

    const float* xa = x + ((size_t)fp * 64 + 32) * HW + s;  // fp, channels 32..63
    const float* xb = x + (size_t)n * 64 * HW + s;          // n,  channels 0..31

    u32 lo0 = 0, lo1 = 0, lo2 = 0, lo3 = 0;
    u32 hi0 = 0, hi1 = 0, hi2 = 0, hi3 = 0;
#pragma unroll
    for (int c = 0; c < 32; c++) {
        float4 va = *(const float4*)(xa + (size_t)c * HW);
        lo0 |= (__float_as_uint(va.x) >> 31) << c;
        lo1 |= (__float_as_uint(va.y) >> 31) << c;
        lo2 |= (__float_as_uint(va.z) >> 31) << c;
        lo3 |= (__float_as_uint(va.w) >> 31) << c;
        float4 vb = *(const float4*)(xb + (size_t)c * HW);
        hi0 |= (__float_as_uint(vb.x) >> 31) << c;
        hi1 |= (__float_as_uint(vb.y) >> 31) << c;
        hi2 |= (__float_as_uint(vb.z) >> 31) << c;
        hi3 |= (__float_as_uint(vb.w) >> 31) << c;
    }
    u64* dst = px + (size_t)n * HW + s;
    dst[0] = ((u64)hi0 << 32) | lo0;
    dst[1] = ((u64)hi1 << 32) | lo1;
    dst[2] = ((u64)hi2 << 32) | lo2;
    dst[3] = ((u64)hi3 << 32) | lo3;
}

// ---------------------------------------------------------------------------
// Kernel 3: binary conv via xor+popcount.
// Block = 256 threads mapped as 64(w) x 4(h): per-o stores are 256B contiguous
// per wave. Each thread computes all 64 output channels for one (n,h,w).
// OOB taps: branch-free via mask-AND; each invalid tap adds constant 32 so its
// contribution 576-2*cnt term is exactly 0.
// ---------------------------------------------------------------------------
__global__ __launch_bounds__(256) void bconv_kernel(const u64* __restrict__ px,
                                                    const u64* __restrict__ pw,
                                                    const float* __restrict__ scale,
                                                    float* __restrict__ out) {
    const int w = (blockIdx.x << 6) + (threadIdx.x & 63);
    const int h = (blockIdx.y << 2) + (threadIdx.x >> 6);
    const int n = blockIdx.z;
    const u64* base = px + (size_t)n * HW;

    u64 xv[9];
    u64 mk[9];
    int ninv = 0;
#pragma unroll
    for (int dh = -1; dh <= 1; dh++) {
#pragma unroll
        for (int dw = -1; dw <= 1; dw++) {
            const int k = (dh + 1) * 3 + (dw + 1);
            const int hh = h + dh, ww = w + dw;
            const bool valid = (hh >= 0) && (hh < 256) && (ww >= 0) && (ww < 256);
            const int hc = min(max(hh, 0), 255);
            const int wc = min(max(ww, 0), 255);
            xv[k] = base[hc * WD + wc];     // clamped address: always in-bounds
            mk[k] = valid ? ~0ull : 0ull;   // mask kills OOB contribution
            ninv += valid ? 0 : 1;
        }
    }
    const int basecnt = 32 * ninv;

    float* op = out + (size_t)n * 64 * HW + h * WD + w;
    for (int o = 0; o < 64; o++) {
        const u64* wp = pw + o * 9;   // wave-uniform -> scalar loads
        int cnt = basecnt;
#pragma unroll
        for (int k = 0; k < 9; k++) {
            cnt += __popcll((xv[k] ^ wp[k]) & mk[k]);
        }
        op[(size_t)o * HW] = scale[o] * (float)(576 - 2 * cnt);
    }
}

// ---------------------------------------------------------------------------
extern "C" void kernel_launch(void* const* d_in, const int* in_sizes, int n_in,
                              void* d_out, int out_size, void* d_ws, size_t ws_size,
                              hipStream_t stream) {
    (void)in_sizes; (void)n_in; (void)out_size; (void)ws_size;
    const float* x  = (const float*)d_in[0];
    const float* wt = (const float*)d_in[1];
    float* out = (float*)d_out;

    // workspace layout: px (12*65536 u64 = 6.0 MiB) | pw (576 u64) | scale (64 f32)
    u64* px = (u64*)d_ws;
    u64* pw = px + (size_t)12 * HW;
    float* scale = (float*)(pw + 576);

    pack_w_kernel<<<1, 64, 0, stream>>>(wt, pw, scale);
    pack_x_kernel<<<768, 256, 0, stream>>>(x, px);
    bconv_kernel<<<dim3(4, 64, 12), 256, 0, stream>>>(px, pw, scale, out);
}

// Round 2
// 384.678 us; speedup vs baseline: 1.0667x; 1.0667x over previous
//
#include <hip/hip_runtime.h>
#include <stdint.h>

typedef unsigned long long u64;
typedef unsigned int u32;

#define HW 65536   // 256*256
#define WD 256

// ---------------------------------------------------------------------------
// Kernel 1: pack weights. 64 blocks (one per o), 64 lanes (one per i).
// pw[o][k] bit i = signbit(w[o][i][kh][kw]) -- built with __ballot (bit=lane).
// scale[o] = mean|w[o]| via wave shuffle reduction.
// ---------------------------------------------------------------------------
__global__ __launch_bounds__(64) void pack_w_kernel(const float* __restrict__ wt,
                                                    u64* __restrict__ pw,
                                                    float* __restrict__ scale) {
    const int o = blockIdx.x;
    const int i = threadIdx.x;          // lane == input channel == bit index
    const float* p = wt + o * 576 + i * 9;
    float v[9];
    float s = 0.f;
#pragma unroll
    for (int k = 0; k < 9; k++) { v[k] = p[k]; s += fabsf(v[k]); }
#pragma unroll
    for (int k = 0; k < 9; k++) {
        u64 m = __ballot((__float_as_uint(v[k]) >> 31) != 0u);
        if (i == 0) pw[o * 9 + k] = m;
    }
#pragma unroll
    for (int off = 32; off > 0; off >>= 1) s += __shfl_down(s, off);
    if (i == 0) scale[o] = s * (1.0f / 576.0f);
}

// ---------------------------------------------------------------------------
// Kernel 2: pack activations WITH the temporal channel shift folded in.
// y[n=(b,t)][c] = x[b*3+(t+2)%3][32+c]  for c in [0,32)  -> bits 0..31
//              = x[n][c-32]             for c in [32,64) -> bits 32..63
// Each thread packs 4 consecutive spatial positions via float4 loads.
// ---------------------------------------------------------------------------
__global__ __launch_bounds__(256) void pack_x_kernel(const float* __restrict__ x,
                                                     u64* __restrict__ px) {
    const int n = blockIdx.x >> 6;                                // frame 0..11
    const int s = ((blockIdx.x & 63) << 10) + (threadIdx.x << 2); // spatial pos, 4/thread
    const int b = n / 3;
    const int t = n - b * 3;
    const int fp = b * 3 + (t + 2) % 3;                           // source frame for low bits

    const float* xa = x + ((size_t)fp * 64 + 32) * HW + s;  // fp, channels 32..63
    const float* xb = x + (size_t)n * 64 * HW + s;          // n,  channels 0..31

    u32 lo0 = 0, lo1 = 0, lo2 = 0, lo3 = 0;
    u32 hi0 = 0, hi1 = 0, hi2 = 0, hi3 = 0;
#pragma unroll
    for (int c = 0; c < 32; c++) {
        float4 va = *(const float4*)(xa + (size_t)c * HW);
        lo0 |= (__float_as_uint(va.x) >> 31) << c;
        lo1 |= (__float_as_uint(va.y) >> 31) << c;
        lo2 |= (__float_as_uint(va.z) >> 31) << c;
        lo3 |= (__float_as_uint(va.w) >> 31) << c;
        float4 vb = *(const float4*)(xb + (size_t)c * HW);
        hi0 |= (__float_as_uint(vb.x) >> 31) << c;
        hi1 |= (__float_as_uint(vb.y) >> 31) << c;
        hi2 |= (__float_as_uint(vb.z) >> 31) << c;
        hi3 |= (__float_as_uint(vb.w) >> 31) << c;
    }
    u64* dst = px + (size_t)n * HW + s;
    dst[0] = ((u64)hi0 << 32) | lo0;
    dst[1] = ((u64)hi1 << 32) | lo1;
    dst[2] = ((u64)hi2 << 32) | lo2;
    dst[3] = ((u64)hi3 << 32) | lo3;
}

// ---------------------------------------------------------------------------
// Kernel 3: binary conv via xor+popcount.
// Block = 256 threads mapped as 64(w) x 4(h): per-o stores are 256B contiguous
// per wave. Each thread computes all 64 output channels for one (n,h,w).
// Interior blocks (48%, uniform branch) skip the OOB mask entirely;
// border blocks use mask-AND + constant 32*ninv correction (branch-free/lane).
// ---------------------------------------------------------------------------
__global__ __launch_bounds__(256) void bconv_kernel(const u64* __restrict__ px,
                                                    const u64* __restrict__ pw,
                                                    const float* __restrict__ scale,
                                                    float* __restrict__ out) {
    const int w = (blockIdx.x << 6) + (threadIdx.x & 63);
    const int h = (blockIdx.y << 2) + (threadIdx.x >> 6);
    const int n = blockIdx.z;
    const u64* base = px + (size_t)n * HW;

    const bool edge_block = (blockIdx.x == 0) | (blockIdx.x == 3) |
                            (blockIdx.y == 0) | (blockIdx.y == 63);

    u64 xv[9];
    float* op = out + (size_t)n * 64 * HW + h * WD + w;

    if (!edge_block) {
        // all 9 taps in-bounds for every lane
#pragma unroll
        for (int dh = -1; dh <= 1; dh++)
#pragma unroll
            for (int dw = -1; dw <= 1; dw++)
                xv[(dh + 1) * 3 + (dw + 1)] = base[(h + dh) * WD + (w + dw)];

#pragma unroll 4
        for (int o = 0; o < 64; o++) {
            const u64* wp = pw + o * 9;            // wave-uniform -> scalar loads
            int cnt = 0;
#pragma unroll
            for (int k = 0; k < 9; k++) cnt += __popcll(xv[k] ^ wp[k]);
            const float sc = scale[o];
            __builtin_nontemporal_store(fmaf(-2.f * sc, (float)cnt, 576.f * sc),
                                        op + (size_t)o * HW);
        }
    } else {
        u64 mk[9];
        int ninv = 0;
#pragma unroll
        for (int dh = -1; dh <= 1; dh++) {
#pragma unroll
            for (int dw = -1; dw <= 1; dw++) {
                const int k = (dh + 1) * 3 + (dw + 1);
                const int hh = h + dh, ww = w + dw;
                const bool valid = (hh >= 0) && (hh < 256) && (ww >= 0) && (ww < 256);
                const int hc = min(max(hh, 0), 255);
                const int wc = min(max(ww, 0), 255);
                xv[k] = base[hc * WD + wc];     // clamped address: always in-bounds
                mk[k] = valid ? ~0ull : 0ull;   // mask kills OOB contribution
                ninv += valid ? 0 : 1;
            }
        }
        const int basecnt = 32 * ninv;          // makes each OOB tap contribute exactly 0

#pragma unroll 4
        for (int o = 0; o < 64; o++) {
            const u64* wp = pw + o * 9;
            int cnt = basecnt;
#pragma unroll
            for (int k = 0; k < 9; k++) cnt += __popcll((xv[k] ^ wp[k]) & mk[k]);
            const float sc = scale[o];
            __builtin_nontemporal_store(fmaf(-2.f * sc, (float)cnt, 576.f * sc),
                                        op + (size_t)o * HW);
        }
    }
}

// ---------------------------------------------------------------------------
extern "C" void kernel_launch(void* const* d_in, const int* in_sizes, int n_in,
                              void* d_out, int out_size, void* d_ws, size_t ws_size,
                              hipStream_t stream) {
    (void)in_sizes; (void)n_in; (void)out_size; (void)ws_size;
    const float* x  = (const float*)d_in[0];
    const float* wt = (const float*)d_in[1];
    float* out = (float*)d_out;

    // workspace layout: px (12*65536 u64 = 6.0 MiB) | pw (576 u64) | scale (64 f32)
    u64* px = (u64*)d_ws;
    u64* pw = px + (size_t)12 * HW;
    float* scale = (float*)(pw + 576);

    pack_w_kernel<<<64, 64, 0, stream>>>(wt, pw, scale);
    pack_x_kernel<<<768, 256, 0, stream>>>(x, px);
    bconv_kernel<<<dim3(4, 64, 12), 256, 0, stream>>>(px, pw, scale, out);
}